// Round 3
// baseline (145.043 us; speedup 1.0000x reference)
//
#include <hip/hip_runtime.h>
#include <math.h>

#define BSZ    8192
#define DDIM   256
#define SCALE  33.33333333333333f   // 1/0.03
#define C_OFF  34.0f                // fixed LSE offset: |sim*SCALE| <= 33.34
#define SC_L2E 48.08983470f         // SCALE * log2(e)
#define C2     49.05163139f         // C_OFF * log2(e)

typedef float floatx4 __attribute__((ext_vector_type(4)));
typedef long long fp8x8;            // 8 x fp8 e4m3 = one MFMA operand (2 VGPRs)

// pack 8 fp32 -> 8 fp8 e4m3 (HW cvt; format matches the fp8 MFMA operand)
__device__ __forceinline__ fp8x8 cvt8_f8(const float* __restrict__ g)
{
    const float4 lo = *(const float4*)g;
    const float4 hi = *(const float4*)(g + 4);
    int a = __builtin_amdgcn_cvt_pk_fp8_f32(lo.x, lo.y, 0, false);
    a     = __builtin_amdgcn_cvt_pk_fp8_f32(lo.z, lo.w, a, true);
    int b = __builtin_amdgcn_cvt_pk_fp8_f32(hi.x, hi.y, 0, false);
    b     = __builtin_amdgcn_cvt_pk_fp8_f32(hi.z, hi.w, b, true);
    int2 r; r.x = a; r.y = b;
    return *(fp8x8*)&r;
}

// ---------------------------------------------------------------- prep (unchanged)
__global__ __launch_bounds__(256) void prep_kernel(
    const float* __restrict__ za, const float* __restrict__ zt,
    unsigned char* __restrict__ za_f8, unsigned char* __restrict__ zt_perm,
    float* __restrict__ zbase)
{
    const int bid = blockIdx.x, tid = threadIdx.x;
    if (bid < 1024) {
        const int i = (bid * 256 + tid) * 8;
        *(fp8x8*)(za_f8 + i) = cvt8_f8(za + i);
        if (bid < 16) {
            const int z = bid * 1024 + tid * 4;
            *(float4*)&zbase[z] = (float4){0.f, 0.f, 0.f, 0.f};
            if (bid == 0 && tid == 0) {
                zbase[16384] = 0.f;          // total
                ((int*)zbase)[16385] = 0;    // flag
                ((int*)zbase)[16386] = 0;    // cnt
            }
        }
    } else {
        const int S     = (bid - 1024) * 256 + tid;   // global 8-B slot id
        const int chunk = S >> 9, P = S & 511;
        const int col   = P >> 2, sp = P & 3;
        const int sl    = sp ^ ((col >> 2) & 3);
        const int cb    = chunk >> 3, kc = chunk & 7;
        const float* src = zt + (size_t)(cb * 128 + col) * DDIM + kc * 32 + sl * 8;
        *(fp8x8*)(zt_perm + (size_t)S * 8) = cvt8_f8(src);
    }
}

// ---------------------------------------------------------------- sim
// ROUND-3: NO LDS STAGING FOR B, NO K-LOOP BARRIERS.
// Round-2 A/B proved barrier-count/staging-BW is NOT the bottleneck: halving
// barriers per FLOP left dur/MfmaUtil/VALUBusy identical (~54us/24%/31%).
// Diagnosis: s_barrier lockstep -> all waves do MFMA phase together, then
// epilogue (exp2/VALU) together; the two pipes never overlap (24+31=55%,
// 45% dead). zt_perm is 2MB = fully L2-resident (round-2 FETCH: 64MB logical
// B-reads -> only 9.4MB HBM), and same-strip blocks (bid stride 16) already
// land on one XCD -> B is L2-local. So read B fragments DIRECTLY global->VGPR
// (each fragment: 64 lanes cover one contiguous 512B span = perfectly
// coalesced). Zero barriers in the K loop -> waves free-run and de-phase ->
// one wave's epilogue overlaps another's MFMAs. 256-thr blocks, grid 1024 =
// exactly 4 blocks/CU (launch_bounds(256,4): 16 waves/CU, VGPR cap 128).
__global__ __launch_bounds__(256, 4) void sim_fused(
    const unsigned char* __restrict__ za_f8, const unsigned char* __restrict__ zt_perm,
    const int* __restrict__ pid,
    float* __restrict__ s_row, float* __restrict__ s_col,
    float* __restrict__ posv)
{
    __shared__ int   pidc[512];
    __shared__ float colsum[512];

    const int bid   = blockIdx.x;
    const int strip = bid & 15, band = bid >> 4;          // band 0..63
    const int row0  = band * 128, scol0 = strip * 512;
    const int tid   = threadIdx.x, lane = tid & 63, wid = tid >> 6;  // wid 0..3
    const int q     = lane >> 4, lc = lane & 15;
    const int rbase = row0 + wid * 32;
    const int qs8   = (q ^ ((lc >> 2) & 3)) * 8;   // swizzled 8-B k-slot offset

    pidc[tid]         = pid[scol0 + tid];
    pidc[tid + 256]   = pid[scol0 + tid + 256];
    colsum[tid]       = 0.f;
    colsum[tid + 256] = 0.f;

    // A fragments resident: af[m][kc] = A[rbase+m*16+lc][kc*32 + q*8 ..+8] (fp8)
    fp8x8 af[2][8];
    #pragma unroll
    for (int m = 0; m < 2; m++) {
        const unsigned char* ga = za_f8 + (size_t)(rbase + m * 16 + lc) * DDIM + q * 8;
        #pragma unroll
        for (int kc = 0; kc < 8; kc++)
            af[m][kc] = *(const fp8x8*)(ga + kc * 32);
    }

    int prw[2][4];
    #pragma unroll
    for (int m = 0; m < 2; m++)
        #pragma unroll
        for (int r = 0; r < 4; r++)
            prw[m][r] = pid[rbase + m * 16 + q * 4 + r];

    __syncthreads();   // pidc/colsum visible; only other barrier is before colsum flush

    // per-lane B base: strip's 128KB + lane's (col,k-slot) offset.
    // fragment n of sub-chunk (C,j) lives at  C*16384 + j*4096 + n*512  from here,
    // and the wave's 64 lanes cover that 512B span exactly once (coalesced).
    const unsigned char* bb = zt_perm + (size_t)strip * 131072 + lc * 32 + qs8;

    float rowp[8] = {0.f, 0.f, 0.f, 0.f, 0.f, 0.f, 0.f, 0.f};
    const int diag_t = (row0 - scol0) >> 7;   // tile holding the diagonal (if in [0,4))

    for (int t = 0; t < 4; t++) {
        floatx4 acc[2][8];
        #pragma unroll
        for (int m = 0; m < 2; m++)
            #pragma unroll
            for (int n = 0; n < 8; n++)
                acc[m][n] = (floatx4){0.f, 0.f, 0.f, 0.f};

        #pragma unroll
        for (int c2 = 0; c2 < 2; c2++) {     // two 16KB chunks per tile
            const unsigned char* bc = bb + (size_t)(t * 2 + c2) * 16384;
            #pragma unroll
            for (int j = 0; j < 4; j++) {    // four 32-k sub-chunks
                const int kc = c2 * 4 + j;
                fp8x8 bfr[8];
                #pragma unroll
                for (int n = 0; n < 8; n++)
                    bfr[n] = *(const fp8x8*)(bc + j * 4096 + n * 512);

                #pragma unroll
                for (int m = 0; m < 2; m++)
                    #pragma unroll
                    for (int n = 0; n < 8; n++)
                        acc[m][n] = __builtin_amdgcn_mfma_f32_16x16x32_fp8_fp8(
                            af[m][kc], bfr[n], acc[m][n], 0, 0, 0);
            }
        }

        // ---------- epilogue for tile t
        int pc[8];
        #pragma unroll
        for (int n = 0; n < 8; n++) pc[n] = pidc[t * 128 + n * 16 + lc];

        float colp[8] = {0.f, 0.f, 0.f, 0.f, 0.f, 0.f, 0.f, 0.f};
        #pragma unroll
        for (int m = 0; m < 2; m++) {
            #pragma unroll
            for (int r = 0; r < 4; r++) {
                const int pr = prw[m][r];
                float rsum = 0.f;
                #pragma unroll
                for (int n = 0; n < 8; n++) {
                    float e = __builtin_amdgcn_exp2f(fmaf(acc[m][n][r], SC_L2E, -C2));
                    e = (pr != pc[n]) ? e : 0.f;
                    rsum += e;
                    colp[n] += e;
                }
                rowp[m * 4 + r] += rsum;
            }
        }

        if (t == diag_t) {   // diagonal fixup — constant-index select chains only
            #pragma unroll
            for (int m = 0; m < 2; m++) {
                const int nstar = wid * 2 + m;
                #pragma unroll
                for (int r = 0; r < 4; r++) {
                    float v = 0.f;
                    #pragma unroll
                    for (int n = 0; n < 8; n++)
                        v = (n == nstar) ? acc[m][n][r] : v;   // cndmask chain
                    float e = __builtin_amdgcn_exp2f(fmaf(v, SC_L2E, -C2));
                    const bool own = (lc == q * 4 + r);
                    e = own ? e : 0.f;
                    rowp[m * 4 + r] += e;
                    #pragma unroll
                    for (int n = 0; n < 8; n++)
                        colp[n] += (n == nstar) ? e : 0.f;     // cndmask chain
                    if (own) posv[rbase + m * 16 + q * 4 + r] = v * SCALE;
                }
            }
        }

        #pragma unroll
        for (int n = 0; n < 8; n++) {
            colp[n] += __shfl_xor(colp[n], 16, 64);
            colp[n] += __shfl_xor(colp[n], 32, 64);
        }
        if (q == 0) {
            #pragma unroll
            for (int n = 0; n < 8; n++)
                atomicAdd(&colsum[t * 128 + n * 16 + lc], colp[n]);
        }
    }

    // ---------- row sums: reduce over lc (cols), one atomic per row
    #pragma unroll
    for (int i = 0; i < 8; i++) {
        rowp[i] += __shfl_xor(rowp[i], 1, 64);
        rowp[i] += __shfl_xor(rowp[i], 2, 64);
        rowp[i] += __shfl_xor(rowp[i], 4, 64);
        rowp[i] += __shfl_xor(rowp[i], 8, 64);
    }
    float rw = rowp[0];
    #pragma unroll
    for (int idx = 1; idx < 8; idx++)
        rw = (lc == idx) ? rowp[idx] : rw;
    if (lc < 8)
        atomicAdd(&s_row[rbase + (lc >> 2) * 16 + q * 4 + (lc & 3)], rw);

    // ---------- col sums
    __syncthreads();
    atomicAdd(&s_col[scol0 + tid], colsum[tid]);
    atomicAdd(&s_col[scol0 + tid + 256], colsum[tid + 256]);
}

// ---------------------------------------------------------------- finalize (+ scalar write)
__global__ __launch_bounds__(256) void finalize_rows(
    const int* __restrict__ pid,
    const float* __restrict__ s_row, const float* __restrict__ s_col,
    const float* __restrict__ posv,
    float* __restrict__ total, int* __restrict__ flag, int* __restrict__ cnt,
    float* __restrict__ out)
{
    const int i = blockIdx.x * 256 + threadIdx.x;
    const float p = posv[i];
    const float c = (logf(s_row[i]) + C_OFF - p)
                  + (logf(s_col[i]) + C_OFF - p);

    float v = c;
    #pragma unroll
    for (int off = 32; off > 0; off >>= 1) v += __shfl_down(v, off, 64);
    if ((threadIdx.x & 63) == 0) atomicAdd(total, v);

    const unsigned long long m = __ballot(pid[i] != pid[0]);
    if (m != 0ull && (threadIdx.x & 63) == 0) atomicOr(flag, 1);

    __syncthreads();
    __threadfence();
    if (threadIdx.x == 0) {
        const int done = atomicAdd(cnt, 1);
        if (done == (int)gridDim.x - 1) {
            const float t = atomicAdd(total, 0.0f);
            const int   f = atomicOr(flag, 0);
            out[0] = f ? t / (2.0f * (float)BSZ) : 0.0f;
        }
    }
}

// ---------------------------------------------------------------- launcher
extern "C" void kernel_launch(void* const* d_in, const int* in_sizes, int n_in,
                              void* d_out, int out_size, void* d_ws, size_t ws_size,
                              hipStream_t stream)
{
    const float* za  = (const float*)d_in[0];
    const float* zt  = (const float*)d_in[1];
    const int*   pid = (const int*)d_in[2];
    float* out = (float*)d_out;

    // ws: za_f8 2MB | zt_perm 2MB | s_row[8192] s_col[8192] total flag cnt posv[8192]
    unsigned char* za_f8   = (unsigned char*)d_ws;
    unsigned char* zt_perm = za_f8 + (size_t)BSZ * DDIM;
    float*  s_row   = (float*)(zt_perm + (size_t)BSZ * DDIM);
    float*  s_col   = s_row + BSZ;
    float*  total   = s_col + BSZ;
    int*    flag    = (int*)(total + 1);
    int*    cnt     = flag + 1;
    float*  posv    = (float*)(cnt + 1);

    prep_kernel<<<dim3(2048), 256, 0, stream>>>(za, zt, za_f8, zt_perm, s_row);

    sim_fused<<<dim3(1024), 256, 0, stream>>>(za_f8, zt_perm, pid,
                                              s_row, s_col, posv);

    finalize_rows<<<dim3(BSZ / 256), 256, 0, stream>>>(
        pid, s_row, s_col, posv, total, flag, cnt, out);
}

// Round 4
// 125.652 us; speedup vs baseline: 1.1543x; 1.1543x over previous
//
#include <hip/hip_runtime.h>
#include <math.h>

#define BSZ    8192
#define DDIM   256
#define SCALE  33.33333333333333f   // 1/0.03
#define C_OFF  34.0f                // fixed LSE offset: |sim*SCALE| <= 33.34
#define SC_L2E 48.08983470f         // SCALE * log2(e)
#define C2     49.05163139f         // C_OFF * log2(e)

typedef float floatx4 __attribute__((ext_vector_type(4)));
typedef long long fp8x8;            // 8 x fp8 e4m3 = one MFMA operand (2 VGPRs)

// pack 8 fp32 -> 8 fp8 e4m3 (HW cvt; format matches the fp8 MFMA operand)
__device__ __forceinline__ fp8x8 cvt8_f8(const float* __restrict__ g)
{
    const float4 lo = *(const float4*)g;
    const float4 hi = *(const float4*)(g + 4);
    int a = __builtin_amdgcn_cvt_pk_fp8_f32(lo.x, lo.y, 0, false);
    a     = __builtin_amdgcn_cvt_pk_fp8_f32(lo.z, lo.w, a, true);
    int b = __builtin_amdgcn_cvt_pk_fp8_f32(hi.x, hi.y, 0, false);
    b     = __builtin_amdgcn_cvt_pk_fp8_f32(hi.z, hi.w, b, true);
    int2 r; r.x = a; r.y = b;
    return *(fp8x8*)&r;
}

// ---------------------------------------------------------------- prep (unchanged)
__global__ __launch_bounds__(256) void prep_kernel(
    const float* __restrict__ za, const float* __restrict__ zt,
    unsigned char* __restrict__ za_f8, unsigned char* __restrict__ zt_perm,
    float* __restrict__ zbase)
{
    const int bid = blockIdx.x, tid = threadIdx.x;
    if (bid < 1024) {
        const int i = (bid * 256 + tid) * 8;
        *(fp8x8*)(za_f8 + i) = cvt8_f8(za + i);
        if (bid < 16) {
            const int z = bid * 1024 + tid * 4;
            *(float4*)&zbase[z] = (float4){0.f, 0.f, 0.f, 0.f};
            if (bid == 0 && tid == 0) {
                zbase[16384] = 0.f;          // total
                ((int*)zbase)[16385] = 0;    // flag
                ((int*)zbase)[16386] = 0;    // cnt
            }
        }
    } else {
        const int S     = (bid - 1024) * 256 + tid;   // global 8-B slot id
        const int chunk = S >> 9, P = S & 511;
        const int col   = P >> 2, sp = P & 3;
        const int sl    = sp ^ ((col >> 2) & 3);
        const int cb    = chunk >> 3, kc = chunk & 7;
        const float* src = zt + (size_t)(cb * 128 + col) * DDIM + kc * 32 + sl * 8;
        *(fp8x8*)(zt_perm + (size_t)S * 8) = cvt8_f8(src);
    }
}

// ---------------------------------------------------------------- sim
// ROUND-4: same barrier-free, no-LDS-B structure as round 3, but
// __launch_bounds__(256, 2).
// MEASURED launch_bounds model on this kernel family (rocprof VGPR_Count):
//   arg2=2 -> natural allocation (112-120 VGPR, no spill)   [R0, R2]
//   arg2=4 -> hard 64-VGPR cap -> catastrophic spills        [R1, R3]
// Round 3's structure was never evaluated (its 81us was spill-dominated:
// FETCH 74MB / WRITE 84MB scratch). VGPR ~112 <= 128 already permits
// 16 waves/CU (4 blocks) by hardware limits; no aggressive bound needed.
// Structure rationale (unchanged): zt_perm (2MB) is L2-resident; B fragments
// are read directly global->VGPR (each fragment = contiguous 512B per wave,
// perfectly coalesced); zero K-loop barriers -> waves free-run and de-phase
// -> epilogue VALU/trans overlaps other waves' MFMAs.
__global__ __launch_bounds__(256, 2) void sim_fused(
    const unsigned char* __restrict__ za_f8, const unsigned char* __restrict__ zt_perm,
    const int* __restrict__ pid,
    float* __restrict__ s_row, float* __restrict__ s_col,
    float* __restrict__ posv)
{
    __shared__ int   pidc[512];
    __shared__ float colsum[512];

    const int bid   = blockIdx.x;
    const int strip = bid & 15, band = bid >> 4;          // band 0..63
    const int row0  = band * 128, scol0 = strip * 512;
    const int tid   = threadIdx.x, lane = tid & 63, wid = tid >> 6;  // wid 0..3
    const int q     = lane >> 4, lc = lane & 15;
    const int rbase = row0 + wid * 32;
    const int qs8   = (q ^ ((lc >> 2) & 3)) * 8;   // swizzled 8-B k-slot offset

    pidc[tid]         = pid[scol0 + tid];
    pidc[tid + 256]   = pid[scol0 + tid + 256];
    colsum[tid]       = 0.f;
    colsum[tid + 256] = 0.f;

    // A fragments resident: af[m][kc] = A[rbase+m*16+lc][kc*32 + q*8 ..+8] (fp8)
    fp8x8 af[2][8];
    #pragma unroll
    for (int m = 0; m < 2; m++) {
        const unsigned char* ga = za_f8 + (size_t)(rbase + m * 16 + lc) * DDIM + q * 8;
        #pragma unroll
        for (int kc = 0; kc < 8; kc++)
            af[m][kc] = *(const fp8x8*)(ga + kc * 32);
    }

    int prw[2][4];
    #pragma unroll
    for (int m = 0; m < 2; m++)
        #pragma unroll
        for (int r = 0; r < 4; r++)
            prw[m][r] = pid[rbase + m * 16 + q * 4 + r];

    __syncthreads();   // pidc/colsum visible; only other barrier is before colsum flush

    // per-lane B base: strip's 128KB + lane's (col,k-slot) offset.
    // fragment n of sub-chunk (C,j) lives at  C*16384 + j*4096 + n*512  from here,
    // and the wave's 64 lanes cover that 512B span exactly once (coalesced).
    const unsigned char* bb = zt_perm + (size_t)strip * 131072 + lc * 32 + qs8;

    float rowp[8] = {0.f, 0.f, 0.f, 0.f, 0.f, 0.f, 0.f, 0.f};
    const int diag_t = (row0 - scol0) >> 7;   // tile holding the diagonal (if in [0,4))

    for (int t = 0; t < 4; t++) {
        floatx4 acc[2][8];
        #pragma unroll
        for (int m = 0; m < 2; m++)
            #pragma unroll
            for (int n = 0; n < 8; n++)
                acc[m][n] = (floatx4){0.f, 0.f, 0.f, 0.f};

        #pragma unroll
        for (int c2 = 0; c2 < 2; c2++) {     // two 16KB chunks per tile
            const unsigned char* bc = bb + (size_t)(t * 2 + c2) * 16384;
            #pragma unroll
            for (int j = 0; j < 4; j++) {    // four 32-k sub-chunks
                const int kc = c2 * 4 + j;
                fp8x8 bfr[8];
                #pragma unroll
                for (int n = 0; n < 8; n++)
                    bfr[n] = *(const fp8x8*)(bc + j * 4096 + n * 512);

                #pragma unroll
                for (int m = 0; m < 2; m++)
                    #pragma unroll
                    for (int n = 0; n < 8; n++)
                        acc[m][n] = __builtin_amdgcn_mfma_f32_16x16x32_fp8_fp8(
                            af[m][kc], bfr[n], acc[m][n], 0, 0, 0);
            }
        }

        // ---------- epilogue for tile t
        int pc[8];
        #pragma unroll
        for (int n = 0; n < 8; n++) pc[n] = pidc[t * 128 + n * 16 + lc];

        float colp[8] = {0.f, 0.f, 0.f, 0.f, 0.f, 0.f, 0.f, 0.f};
        #pragma unroll
        for (int m = 0; m < 2; m++) {
            #pragma unroll
            for (int r = 0; r < 4; r++) {
                const int pr = prw[m][r];
                float rsum = 0.f;
                #pragma unroll
                for (int n = 0; n < 8; n++) {
                    float e = __builtin_amdgcn_exp2f(fmaf(acc[m][n][r], SC_L2E, -C2));
                    e = (pr != pc[n]) ? e : 0.f;
                    rsum += e;
                    colp[n] += e;
                }
                rowp[m * 4 + r] += rsum;
            }
        }

        if (t == diag_t) {   // diagonal fixup — constant-index select chains only
            #pragma unroll
            for (int m = 0; m < 2; m++) {
                const int nstar = wid * 2 + m;
                #pragma unroll
                for (int r = 0; r < 4; r++) {
                    float v = 0.f;
                    #pragma unroll
                    for (int n = 0; n < 8; n++)
                        v = (n == nstar) ? acc[m][n][r] : v;   // cndmask chain
                    float e = __builtin_amdgcn_exp2f(fmaf(v, SC_L2E, -C2));
                    const bool own = (lc == q * 4 + r);
                    e = own ? e : 0.f;
                    rowp[m * 4 + r] += e;
                    #pragma unroll
                    for (int n = 0; n < 8; n++)
                        colp[n] += (n == nstar) ? e : 0.f;     // cndmask chain
                    if (own) posv[rbase + m * 16 + q * 4 + r] = v * SCALE;
                }
            }
        }

        #pragma unroll
        for (int n = 0; n < 8; n++) {
            colp[n] += __shfl_xor(colp[n], 16, 64);
            colp[n] += __shfl_xor(colp[n], 32, 64);
        }
        if (q == 0) {
            #pragma unroll
            for (int n = 0; n < 8; n++)
                atomicAdd(&colsum[t * 128 + n * 16 + lc], colp[n]);
        }
    }

    // ---------- row sums: reduce over lc (cols), one atomic per row
    #pragma unroll
    for (int i = 0; i < 8; i++) {
        rowp[i] += __shfl_xor(rowp[i], 1, 64);
        rowp[i] += __shfl_xor(rowp[i], 2, 64);
        rowp[i] += __shfl_xor(rowp[i], 4, 64);
        rowp[i] += __shfl_xor(rowp[i], 8, 64);
    }
    float rw = rowp[0];
    #pragma unroll
    for (int idx = 1; idx < 8; idx++)
        rw = (lc == idx) ? rowp[idx] : rw;
    if (lc < 8)
        atomicAdd(&s_row[rbase + (lc >> 2) * 16 + q * 4 + (lc & 3)], rw);

    // ---------- col sums
    __syncthreads();
    atomicAdd(&s_col[scol0 + tid], colsum[tid]);
    atomicAdd(&s_col[scol0 + tid + 256], colsum[tid + 256]);
}

// ---------------------------------------------------------------- finalize (+ scalar write)
__global__ __launch_bounds__(256) void finalize_rows(
    const int* __restrict__ pid,
    const float* __restrict__ s_row, const float* __restrict__ s_col,
    const float* __restrict__ posv,
    float* __restrict__ total, int* __restrict__ flag, int* __restrict__ cnt,
    float* __restrict__ out)
{
    const int i = blockIdx.x * 256 + threadIdx.x;
    const float p = posv[i];
    const float c = (logf(s_row[i]) + C_OFF - p)
                  + (logf(s_col[i]) + C_OFF - p);

    float v = c;
    #pragma unroll
    for (int off = 32; off > 0; off >>= 1) v += __shfl_down(v, off, 64);
    if ((threadIdx.x & 63) == 0) atomicAdd(total, v);

    const unsigned long long m = __ballot(pid[i] != pid[0]);
    if (m != 0ull && (threadIdx.x & 63) == 0) atomicOr(flag, 1);

    __syncthreads();
    __threadfence();
    if (threadIdx.x == 0) {
        const int done = atomicAdd(cnt, 1);
        if (done == (int)gridDim.x - 1) {
            const float t = atomicAdd(total, 0.0f);
            const int   f = atomicOr(flag, 0);
            out[0] = f ? t / (2.0f * (float)BSZ) : 0.0f;
        }
    }
}

// ---------------------------------------------------------------- launcher
extern "C" void kernel_launch(void* const* d_in, const int* in_sizes, int n_in,
                              void* d_out, int out_size, void* d_ws, size_t ws_size,
                              hipStream_t stream)
{
    const float* za  = (const float*)d_in[0];
    const float* zt  = (const float*)d_in[1];
    const int*   pid = (const int*)d_in[2];
    float* out = (float*)d_out;

    // ws: za_f8 2MB | zt_perm 2MB | s_row[8192] s_col[8192] total flag cnt posv[8192]
    unsigned char* za_f8   = (unsigned char*)d_ws;
    unsigned char* zt_perm = za_f8 + (size_t)BSZ * DDIM;
    float*  s_row   = (float*)(zt_perm + (size_t)BSZ * DDIM);
    float*  s_col   = s_row + BSZ;
    float*  total   = s_col + BSZ;
    int*    flag    = (int*)(total + 1);
    int*    cnt     = flag + 1;
    float*  posv    = (float*)(cnt + 1);

    prep_kernel<<<dim3(2048), 256, 0, stream>>>(za, zt, za_f8, zt_perm, s_row);

    sim_fused<<<dim3(1024), 256, 0, stream>>>(za_f8, zt_perm, pid,
                                              s_row, s_col, posv);

    finalize_rows<<<dim3(BSZ / 256), 256, 0, stream>>>(
        pid, s_row, s_col, posv, total, flag, cnt, out);
}